// Round 1
// baseline (638.750 us; speedup 1.0000x reference)
//
#include <hip/hip_runtime.h>
#include <math.h>

namespace {
constexpr int Bn = 4;
constexpr int Cn = 256;
constexpr int Kn = 19;
constexpr int HW = 256 * 256;          // 65536
constexpr int P  = Bn * HW;            // 262144 pixels
constexpr float TAUv = 0.07f;
constexpr float EPSv = 1e-12f;

// workspace layout (floats)
constexpr int K0_OFF   = 0;            // [19][256] prototype accumulators
constexpr int K0NT_OFF = 4864;         // [256][19] normalized prototypes (transposed)
constexpr int SUMS_OFF = 9728;         // {loss_sum, num_pos}
constexpr int PART_OFF = 9984;         // [P1_GRID][256] sumsq partials
constexpr int P1_GRID  = 512;
constexpr int ZERO_N   = 9730;
}

__global__ __launch_bounds__(256) void gc_init(float* __restrict__ ws) {
  int i = blockIdx.x * 256 + threadIdx.x;
  if (i < ZERO_N) ws[i] = 0.0f;
}

// Phase 1: k0[k][c] = sum over pixels of pos[k,p] * fnorm[c,p]
__global__ __launch_bounds__(256) void gc_phase1(const float* __restrict__ feat,
                                                 const float* __restrict__ gt,
                                                 float* __restrict__ ws) {
  __shared__ float tile[64 * 256];   // 64 KB exactly; swizzled [p][c ^ (p&31)]
  float* k0   = ws + K0_OFF;
  float* part = ws + PART_OFF;

  const int t    = threadIdx.x;      // t == channel c this thread accumulates
  const int lane = t & 63;           // lane == pixel p this thread stages
  const int wv   = t >> 6;

  float acc[Kn];
#pragma unroll
  for (int k = 0; k < Kn; k++) acc[k] = 0.0f;

  for (int tid = blockIdx.x; tid < P / 64; tid += gridDim.x) {
    const int p0  = tid << 6;
    const int b   = p0 >> 16;              // HW == 65536
    const int hw0 = p0 & (HW - 1);
    const float* fb = feat + (size_t)b * (Cn * HW) + hw0 + lane;
    const float* gb = gt   + (size_t)b * (Kn * HW) + hw0 + lane;

    __syncthreads();   // previous tile (LDS + part) fully consumed

    // stage 64px x 256ch tile; wave wv loads channels [wv*64, wv*64+64)
    float ss = 0.0f;
#pragma unroll 8
    for (int j = 0; j < 64; j++) {
      const int c = (wv << 6) + j;
      const float v = fb[(size_t)c * HW];
      ss += v * v;
      tile[(lane << 8) + (c ^ (lane & 31))] = v;
    }
    part[(blockIdx.x << 8) + t] = ss;      // per-(wave,pixel) sumsq partial

    // positive-class bitmask for pixel p=lane (computed redundantly per wave)
    unsigned my_mask = 0;
#pragma unroll
    for (int k = 0; k < Kn; k++)
      my_mask |= (gb[(size_t)k * HW] == 1.0f) ? (1u << k) : 0u;

    __syncthreads();   // tile + partials visible

    float fss = 0.0f;
#pragma unroll
    for (int q = 0; q < 4; q++) fss += part[(blockIdx.x << 8) + (q << 6) + lane];
    const float my_rn = 1.0f / fmaxf(sqrtf(fss), EPSv);  // rnorm for pixel p=lane

    // accumulate: thread t owns channel c=t, loops over the 64 pixels
#pragma unroll 4
    for (int p = 0; p < 64; p++) {
      const float rp = __shfl(my_rn, p);
      unsigned mp = (unsigned)__shfl((int)my_mask, p);
      mp = __builtin_amdgcn_readfirstlane(mp);           // wave-uniform -> scalar branches
      const float fv = tile[(p << 8) + (t ^ (p & 31))] * rp;
#pragma unroll
      for (int k = 0; k < Kn; k++)
        if (mp & (1u << k)) acc[k] += fv;
    }
  }

#pragma unroll
  for (int k = 0; k < Kn; k++) atomicAdd(&k0[k * 256 + t], acc[k]);
}

// Phase 2: row-normalize k0, store transposed [c][k]
__global__ __launch_bounds__(256) void gc_phase2(float* __restrict__ ws) {
  const float* k0 = ws + K0_OFF;
  float* k0nT = ws + K0NT_OFF;
  const int lane = threadIdx.x & 63;
  const int wv   = threadIdx.x >> 6;
  for (int r = wv; r < Kn; r += 4) {
    float s = 0.0f;
#pragma unroll
    for (int j = 0; j < 4; j++) {
      const float v = k0[r * 256 + (j << 6) + lane];
      s += v * v;
    }
#pragma unroll
    for (int off = 32; off > 0; off >>= 1) s += __shfl_down(s, off);
    s = __shfl(s, 0);
    const float rn = 1.0f / fmaxf(sqrtf(s), EPSv);
#pragma unroll
    for (int j = 0; j < 4; j++) {
      const int c = (j << 6) + lane;
      k0nT[c * Kn + r] = k0[r * 256 + c] * rn;
    }
  }
}

// Phase 3: per-pixel logits + log-softmax + masked loss accumulation
__global__ __launch_bounds__(256) void gc_phase3(const float* __restrict__ feat,
                                                 const float* __restrict__ gt,
                                                 float* __restrict__ ws) {
  const float* k0nT = ws + K0NT_OFF;
  float* sums = ws + SUMS_OFF;

  const int t   = threadIdx.x;
  const int pix = (blockIdx.x << 8) + t;
  const int b   = pix >> 16;
  const int hw  = pix & (HW - 1);
  const float* fb = feat + (size_t)b * (Cn * HW) + hw;

  float dot[Kn];
#pragma unroll
  for (int k = 0; k < Kn; k++) dot[k] = 0.0f;
  float ss = 0.0f;

  // single pass: raw dot products; normalization folded in afterwards
#pragma unroll 2
  for (int c = 0; c < Cn; c++) {
    const float f = fb[(size_t)c * HW];
    ss += f * f;
#pragma unroll
    for (int k = 0; k < Kn; k++) dot[k] = fmaf(f, k0nT[c * Kn + k], dot[k]);
  }

  const float sc = 1.0f / (fmaxf(sqrtf(ss), EPSv) * TAUv);
  float mx = -1e30f;
#pragma unroll
  for (int k = 0; k < Kn; k++) { dot[k] *= sc; mx = fmaxf(mx, dot[k]); }
  float se = 0.0f;
#pragma unroll
  for (int k = 0; k < Kn; k++) se += __expf(dot[k] - mx);
  const float lse = __logf(se) + mx;

  const float* gb = gt + (size_t)b * (Kn * HW) + hw;
  float lsum = 0.0f;
  float npos = 0.0f;
#pragma unroll
  for (int k = 0; k < Kn; k++) {
    if (gb[(size_t)k * HW] == 1.0f) { lsum += lse - dot[k]; npos += 1.0f; }
  }

#pragma unroll
  for (int off = 32; off > 0; off >>= 1) {
    lsum += __shfl_down(lsum, off);
    npos += __shfl_down(npos, off);
  }
  if ((t & 63) == 0) {
    atomicAdd(&sums[0], lsum);
    atomicAdd(&sums[1], npos);
  }
}

__global__ void gc_finalize(const float* __restrict__ ws, float* __restrict__ out) {
  if (threadIdx.x == 0 && blockIdx.x == 0)
    out[0] = ws[SUMS_OFF] / ws[SUMS_OFF + 1];
}

extern "C" void kernel_launch(void* const* d_in, const int* in_sizes, int n_in,
                              void* d_out, int out_size, void* d_ws, size_t ws_size,
                              hipStream_t stream) {
  const float* feat = (const float*)d_in[0];
  const float* gt   = (const float*)d_in[1];
  float* ws  = (float*)d_ws;
  float* out = (float*)d_out;

  gc_init<<<dim3((ZERO_N + 255) / 256), dim3(256), 0, stream>>>(ws);
  gc_phase1<<<dim3(P1_GRID), dim3(256), 0, stream>>>(feat, gt, ws);
  gc_phase2<<<dim3(1), dim3(256), 0, stream>>>(ws);
  gc_phase3<<<dim3(P / 256), dim3(256), 0, stream>>>(feat, gt, ws);
  gc_finalize<<<dim3(1), dim3(64), 0, stream>>>(ws, out);
}